// Round 1
// baseline (403.449 us; speedup 1.0000x reference)
//
#include <hip/hip_runtime.h>

// ---------- types & helpers ----------
typedef unsigned short u16;
typedef float   f32x4  __attribute__((ext_vector_type(4)));
typedef short   short8 __attribute__((ext_vector_type(8)));
typedef __bf16  bf16x8 __attribute__((ext_vector_type(8)));
typedef float   float4v __attribute__((ext_vector_type(4)));
typedef unsigned short u16x4 __attribute__((ext_vector_type(4)));

static __device__ __forceinline__ u16 f2b(float f) {
  union { float f; unsigned u; } v; v.f = f;
  unsigned r = (v.u + 0x7fffu + ((v.u >> 16) & 1u)) >> 16;  // RNE
  return (u16)r;
}
static __device__ __forceinline__ float b2f(u16 h) {
  union { unsigned u; float f; } v; v.u = ((unsigned)h) << 16;
  return v.f;
}
static __device__ __forceinline__ f32x4 mfma_bf16(short8 a, short8 b, f32x4 c) {
  return __builtin_amdgcn_mfma_f32_16x16x32_bf16(
      __builtin_bit_cast(bf16x8, a), __builtin_bit_cast(bf16x8, b), c, 0, 0, 0);
}
// async global->LDS, 16B per lane; lds ptr must be wave-uniform base (HW adds lane*16)
static __device__ __forceinline__ void gload_lds16(const u16* g, u16* l) {
  __builtin_amdgcn_global_load_lds(
      (const __attribute__((address_space(1))) unsigned int*)g,
      (__attribute__((address_space(3))) unsigned int*)l, 16, 0, 0);
}

// ---------- problem constants ----------
#define BB 2
#define TT 2048
#define DD 2048
#define NH 16
#define NKVH 4
#define HD 128
#define MM (BB * TT)          // 4096 rows
#define KVSTR (2 * NKVH * HD) // 1024: KV row = [K(512) | V(512)]

// ---------- fp32 -> bf16 convert ----------
__global__ __launch_bounds__(256) void cvt_f32_bf16(const float* __restrict__ in,
                                                    u16* __restrict__ out, int n4) {
  int stride = gridDim.x * blockDim.x;
  for (int i = blockIdx.x * blockDim.x + threadIdx.x; i < n4; i += stride) {
    float4v v = ((const float4v*)in)[i];
    u16x4 o;
    o[0] = f2b(v[0]); o[1] = f2b(v[1]); o[2] = f2b(v[2]); o[3] = f2b(v[3]);
    ((u16x4*)out)[i] = o;
  }
}

// ---------- RoPE in-place on bf16 (softmax scale folded in for Q) ----------
__global__ __launch_bounds__(256) void rope_kernel(u16* __restrict__ X,
                                                   const float* __restrict__ rope,
                                                   int n_heads, int rowstr, float scale) {
  int idx = blockIdx.x * 256 + threadIdx.x;
  int i  = idx & 63;
  int h  = (idx >> 6) % n_heads;
  int bt = idx / (64 * n_heads);
  int t  = bt & (TT - 1);
  size_t base = (size_t)bt * rowstr + h * HD + i;
  float x1 = b2f(X[base]);
  float x2 = b2f(X[base + 64]);
  float c = rope[t * 128 + 2 * i];
  float s = rope[t * 128 + 2 * i + 1];
  X[base]      = f2b(scale * (x1 * c - x2 * s));
  X[base + 64] = f2b(scale * (x1 * s + x2 * c));
}

// ---------- GEMM (m97 structure): C[M,N] = A[M,K] * W[N,K]^T ----------
// 128x128 tile, 4 waves (2x2), 64x64/wave, BK=32, linear LDS [128][32],
// staged via global_load_lds width=16.
template <bool OUTBF>
__global__ __launch_bounds__(256) void gemm_bt(const u16* __restrict__ A,
                                               const u16* __restrict__ W,
                                               void* __restrict__ Cout,
                                               int M, int N, int K) {
  __shared__ __align__(16) u16 As[128 * 32];
  __shared__ __align__(16) u16 Ws[128 * 32];
  const int tid = threadIdx.x, lane = tid & 63, wid = tid >> 6;
  const int wr = wid >> 1, wc = wid & 1;
  const int brow = blockIdx.y * 128, bcol = blockIdx.x * 128;
  const int l15 = lane & 15, lh = lane >> 4;

  // chunk c (16B): row = c>>2, elem col = (c&3)*8 ; LDS elem off = c*8
  const int c0 = wid * 64 + lane;
  const int c1 = c0 + 256;
  const u16* Ag0 = A + (size_t)(brow + (c0 >> 2)) * K + ((c0 & 3) << 3);
  const u16* Ag1 = A + (size_t)(brow + (c1 >> 2)) * K + ((c1 & 3) << 3);
  const u16* Wg0 = W + (size_t)(bcol + (c0 >> 2)) * K + ((c0 & 3) << 3);
  const u16* Wg1 = W + (size_t)(bcol + (c1 >> 2)) * K + ((c1 & 3) << 3);
  u16* lA0 = &As[(wid * 64) * 8];
  u16* lA1 = &As[(wid * 64 + 256) * 8];
  u16* lW0 = &Ws[(wid * 64) * 8];
  u16* lW1 = &Ws[(wid * 64 + 256) * 8];

  f32x4 acc[4][4];
#pragma unroll
  for (int m = 0; m < 4; ++m)
#pragma unroll
    for (int n = 0; n < 4; ++n) acc[m][n] = (f32x4)0.0f;

  for (int k0 = 0; k0 < K; k0 += 32) {
    __syncthreads();
    gload_lds16(Ag0 + k0, lA0);
    gload_lds16(Ag1 + k0, lA1);
    gload_lds16(Wg0 + k0, lW0);
    gload_lds16(Wg1 + k0, lW1);
    __syncthreads();
    short8 af[4], bfr[4];
#pragma unroll
    for (int m = 0; m < 4; ++m)
      af[m] = *(const short8*)&As[(wr * 64 + m * 16 + l15) * 32 + (lh << 3)];
#pragma unroll
    for (int n = 0; n < 4; ++n)
      bfr[n] = *(const short8*)&Ws[(wc * 64 + n * 16 + l15) * 32 + (lh << 3)];
#pragma unroll
    for (int m = 0; m < 4; ++m)
#pragma unroll
      for (int n = 0; n < 4; ++n)
        acc[m][n] = mfma_bf16(af[m], bfr[n], acc[m][n]);
  }

#pragma unroll
  for (int m = 0; m < 4; ++m)
#pragma unroll
    for (int n = 0; n < 4; ++n)
#pragma unroll
      for (int j = 0; j < 4; ++j) {
        int row = brow + wr * 64 + m * 16 + lh * 4 + j;
        int col = bcol + wc * 64 + n * 16 + l15;
        if (OUTBF)
          ((u16*)Cout)[(size_t)row * N + col] = f2b(acc[m][n][j]);
        else
          ((float*)Cout)[(size_t)row * N + col] = acc[m][n][j];
      }
}

// ---------- V transpose: KVb V-half [b*T+t][kvh*128+d] -> VT[kvh*128+d][b*T+t] ----------
__global__ __launch_bounds__(256) void transpose_v(const u16* __restrict__ KV,
                                                   u16* __restrict__ VT) {
  __shared__ u16 tile[64][72];
  const int r  = threadIdx.x >> 2;         // 0..63
  const int c0 = (threadIdx.x & 3) << 3;   // 0,8,16,24
  const int trow0 = blockIdx.x * 64;       // global row (b*T+t)
  const int d0    = blockIdx.y * 64;       // col within V half [0,512)
  const u16* src = KV + (size_t)(trow0 + r) * KVSTR + NKVH * HD + d0;
  *(short8*)&tile[r][c0]      = *(const short8*)(src + c0);
  *(short8*)&tile[r][c0 + 32] = *(const short8*)(src + c0 + 32);
  __syncthreads();
  u16* dst = VT + (size_t)(d0 + r) * MM + trow0;
  short8 v1, v2;
#pragma unroll
  for (int e = 0; e < 8; ++e) {
    v1[e] = (short)tile[c0 + e][r];
    v2[e] = (short)tile[c0 + 32 + e][r];
  }
  *(short8*)(dst + c0)      = v1;
  *(short8*)(dst + c0 + 32) = v2;
}

// ---------- fused causal GQA flash attention (barrier-free) ----------
// 4 waves / 256 threads per block; each wave owns 32 q-rows (2 groups of 16).
// No KV LDS staging: K fragments read directly from global (L2-resident,
// contiguous 16B), V fragments from pre-transposed VT (contiguous 16B).
// Zero __syncthreads in the main loop; P round-trips per-wave-private LDS.
// Per-wave causal trip count; heavy (high-qt) blocks launch first.
__global__ __launch_bounds__(256, 2) void attn_kernel(const u16* __restrict__ Q,
                                                      const u16* __restrict__ KV,
                                                      const u16* __restrict__ VT,
                                                      u16* __restrict__ Y) {
  __shared__ __align__(16) u16 Ps[4][2][16 * 72];  // per-wave-private, 18432 B

  const int tid = threadIdx.x, lane = tid & 63, wid = tid >> 6;
  const int l15 = lane & 15, lh = lane >> 4;
  const int bid = blockIdx.x;
  const int qt = 15 - (bid >> 5);   // qt descending: heavy blocks first
  const int bh = bid & 31;
  const int h = bh & 15;
  const int b = bh >> 4;
  const int kvh = h >> 2;
  const int row0 = qt * 128 + wid * 32;  // wave's first q row

  const u16* Kb_ = KV + (size_t)b * TT * KVSTR + kvh * HD;
  const u16* Vb_ = VT + (size_t)(kvh * HD) * MM + b * TT;

  short8 ones8;
#pragma unroll
  for (int e = 0; e < 8; ++e) ones8[e] = (short)0x3F80;  // bf16 1.0

  short8 qa[2][4];
#pragma unroll
  for (int g = 0; g < 2; ++g) {
    const u16* qp = Q + (size_t)(b * TT + row0 + g * 16 + l15) * DD + h * HD + (lh << 3);
#pragma unroll
    for (int kk = 0; kk < 4; ++kk) qa[g][kk] = *(const short8*)(qp + kk * 32);
  }

  f32x4 o[2][8];
  f32x4 ol[2];
  float m[2][4];
#pragma unroll
  for (int g = 0; g < 2; ++g) {
    ol[g] = (f32x4)0.0f;
#pragma unroll
    for (int n = 0; n < 8; ++n) o[g][n] = (f32x4)0.0f;
#pragma unroll
    for (int j = 0; j < 4; ++j) m[g][j] = -1e30f;
  }

  u16* myP0 = &Ps[wid][0][0];
  u16* myP1 = &Ps[wid][1][0];

  const int ntiles = (row0 + 95) >> 6;  // cover kv <= row0+31
  for (int it = 0; it < ntiles; ++it) {
    const int kv0 = it * 64;

    // ---- QK^T: K fragments straight from global (shared across both groups)
    f32x4 s[2][4];
#pragma unroll
    for (int g = 0; g < 2; ++g)
#pragma unroll
      for (int nt = 0; nt < 4; ++nt) s[g][nt] = (f32x4)0.0f;

#pragma unroll
    for (int nt = 0; nt < 4; ++nt) {
      const u16* kp = Kb_ + (size_t)(kv0 + nt * 16 + l15) * KVSTR + (lh << 3);
#pragma unroll
      for (int kk = 0; kk < 4; ++kk) {
        short8 kb = *(const short8*)(kp + kk * 32);
        s[0][nt] = mfma_bf16(qa[0][kk], kb, s[0][nt]);
        s[1][nt] = mfma_bf16(qa[1][kk], kb, s[1][nt]);
      }
    }

    // ---- causal mask (skip entirely for fully-unmasked tiles; wave-uniform)
    if (kv0 + 63 > row0) {
#pragma unroll
      for (int g = 0; g < 2; ++g) {
        const int qg = row0 + g * 16 + lh * 4;
#pragma unroll
        for (int j = 0; j < 4; ++j)
#pragma unroll
          for (int nt = 0; nt < 4; ++nt)
            if (kv0 + nt * 16 + l15 > qg + j) s[g][nt][j] = -1e30f;
      }
    }

    // ---- row max (16-lane groups via shfl_xor)
    float mt[2][4];
#pragma unroll
    for (int g = 0; g < 2; ++g)
#pragma unroll
      for (int j = 0; j < 4; ++j)
        mt[g][j] = fmaxf(fmaxf(s[g][0][j], s[g][1][j]), fmaxf(s[g][2][j], s[g][3][j]));
#pragma unroll
    for (int d = 1; d <= 8; d <<= 1)
#pragma unroll
      for (int g = 0; g < 2; ++g)
#pragma unroll
        for (int j = 0; j < 4; ++j) mt[g][j] = fmaxf(mt[g][j], __shfl_xor(mt[g][j], d));

    // ---- defer-max (T13): rescale only when max grew by > 8
    float gmax = mt[0][0] - m[0][0];
#pragma unroll
    for (int g = 0; g < 2; ++g)
#pragma unroll
      for (int j = 0; j < 4; ++j) gmax = fmaxf(gmax, mt[g][j] - m[g][j]);
    if (!__all(gmax <= 8.0f)) {
#pragma unroll
      for (int g = 0; g < 2; ++g)
#pragma unroll
        for (int j = 0; j < 4; ++j) {
          float mn = fmaxf(m[g][j], mt[g][j]);
          float a = __expf(m[g][j] - mn);
          m[g][j] = mn;
          ol[g][j] *= a;
#pragma unroll
          for (int n = 0; n < 8; ++n) o[g][n][j] *= a;
        }
    }

    // ---- P -> per-wave LDS (transpose to A-frag layout); no barrier needed
#pragma unroll
    for (int nt = 0; nt < 4; ++nt)
#pragma unroll
      for (int j = 0; j < 4; ++j) {
        myP0[(lh * 4 + j) * 72 + nt * 16 + l15] = f2b(__expf(s[0][nt][j] - m[0][j]));
        myP1[(lh * 4 + j) * 72 + nt * 16 + l15] = f2b(__expf(s[1][nt][j] - m[1][j]));
      }

    // ---- PV: V^T fragments straight from global (shared across both groups)
#pragma unroll
    for (int c = 0; c < 2; ++c) {
      short8 pa0 = *(const short8*)&myP0[l15 * 72 + c * 32 + (lh << 3)];
      short8 pa1 = *(const short8*)&myP1[l15 * 72 + c * 32 + (lh << 3)];
      ol[0] = mfma_bf16(pa0, ones8, ol[0]);
      ol[1] = mfma_bf16(pa1, ones8, ol[1]);
      const u16* vp = Vb_ + (size_t)l15 * MM + kv0 + c * 32 + (lh << 3);
#pragma unroll
      for (int nt2 = 0; nt2 < 8; ++nt2) {
        short8 vb = *(const short8*)(vp + (size_t)(nt2 * 16) * MM);
        o[0][nt2] = mfma_bf16(pa0, vb, o[0][nt2]);
        o[1][nt2] = mfma_bf16(pa1, vb, o[1][nt2]);
      }
    }
  }

  // ---- epilogue
#pragma unroll
  for (int g = 0; g < 2; ++g) {
    f32x4 inv;
#pragma unroll
    for (int j = 0; j < 4; ++j) inv[j] = __builtin_amdgcn_rcpf(ol[g][j]);
#pragma unroll
    for (int nt2 = 0; nt2 < 8; ++nt2)
#pragma unroll
      for (int j = 0; j < 4; ++j)
        Y[(size_t)(b * TT + row0 + g * 16 + lh * 4 + j) * DD + h * HD + nt2 * 16 + l15] =
            f2b(o[g][nt2][j] * inv[j]);
  }
}

// ---------- launcher ----------
extern "C" void kernel_launch(void* const* d_in, const int* in_sizes, int n_in,
                              void* d_out, int out_size, void* d_ws, size_t ws_size,
                              hipStream_t stream) {
  const float* x    = (const float*)d_in[0];
  const float* rope = (const float*)d_in[1];
  const float* wq   = (const float*)d_in[2];
  const float* wk   = (const float*)d_in[3];
  const float* wv   = (const float*)d_in[4];
  const float* wo   = (const float*)d_in[5];
  float* out = (float*)d_out;

  char* ws = (char*)d_ws;
  u16* xb   = (u16*)ws; ws += (size_t)MM * DD * 2;          // 16.8 MB
  u16* wqb  = (u16*)ws; ws += (size_t)DD * DD * 2;          //  8.4 MB
  u16* wkvb = (u16*)ws; ws += (size_t)KVSTR * DD * 2;       //  4.2 MB (wk|wv rows)
  u16* wob  = (u16*)ws; ws += (size_t)DD * DD * 2;          //  8.4 MB
  u16* Qb   = (u16*)ws; ws += (size_t)MM * DD * 2;          // 16.8 MB
  u16* KVb  = (u16*)ws; ws += (size_t)MM * KVSTR * 2;       //  8.4 MB
  u16* Yb   = (u16*)ws;                                     // 16.8 MB
  // VT (4.2 MB) reuses wqb's space: wqb is dead after the Q GEMM, which runs
  // strictly before transpose_v on this stream.
  u16* VTb  = wqb;

  // 1) converts (wk & wv concatenated into one [1024][2048] weight)
  cvt_f32_bf16<<<2048, 256, 0, stream>>>(x,  xb,  (MM * DD) / 4);
  cvt_f32_bf16<<<2048, 256, 0, stream>>>(wq, wqb, (DD * DD) / 4);
  cvt_f32_bf16<<<1024, 256, 0, stream>>>(wk, wkvb, (NKVH * HD * DD) / 4);
  cvt_f32_bf16<<<1024, 256, 0, stream>>>(wv, wkvb + (size_t)NKVH * HD * DD, (NKVH * HD * DD) / 4);
  cvt_f32_bf16<<<2048, 256, 0, stream>>>(wo, wob, (DD * DD) / 4);

  // 2) projections (KV fused: one N=1024 GEMM -> interleaved [K|V] rows)
  gemm_bt<true><<<dim3(DD / 128, MM / 128), 256, 0, stream>>>(xb, wqb, Qb, MM, DD, DD);
  gemm_bt<true><<<dim3(KVSTR / 128, MM / 128), 256, 0, stream>>>(xb, wkvb, KVb, MM, KVSTR, DD);

  // 3) RoPE (softmax scale folded into Q; V half untouched)
  rope_kernel<<<(MM * NH * 64) / 256, 256, 0, stream>>>(Qb, rope, NH, DD, 0.08838834764831845f);
  rope_kernel<<<(MM * NKVH * 64) / 256, 256, 0, stream>>>(KVb, rope, NKVH, KVSTR, 1.0f);

  // 4) V transpose for direct-global PV fragments, then attention
  transpose_v<<<dim3(MM / 64, (NKVH * HD) / 64), 256, 0, stream>>>(KVb, VTb);
  attn_kernel<<<BB * NH * (TT / 128), 256, 0, stream>>>(Qb, KVb, VTb, Yb);

  // 5) output projection (fp32 out)
  gemm_bt<false><<<dim3(DD / 128, MM / 128), 256, 0, stream>>>(Yb, wob, out, MM, DD, DD);
}

// Round 2
// 279.844 us; speedup vs baseline: 1.4417x; 1.4417x over previous
//
#include <hip/hip_runtime.h>

// ---------- types & helpers ----------
typedef unsigned short u16;
typedef float   f32x4  __attribute__((ext_vector_type(4)));
typedef short   short8 __attribute__((ext_vector_type(8)));
typedef __bf16  bf16x8 __attribute__((ext_vector_type(8)));
typedef float   float4v __attribute__((ext_vector_type(4)));
typedef unsigned short u16x4 __attribute__((ext_vector_type(4)));

static __device__ __forceinline__ u16 f2b(float f) {
  union { float f; unsigned u; } v; v.f = f;
  unsigned r = (v.u + 0x7fffu + ((v.u >> 16) & 1u)) >> 16;  // RNE
  return (u16)r;
}
static __device__ __forceinline__ float b2f(u16 h) {
  union { unsigned u; float f; } v; v.u = ((unsigned)h) << 16;
  return v.f;
}
static __device__ __forceinline__ f32x4 mfma_bf16(short8 a, short8 b, f32x4 c) {
  return __builtin_amdgcn_mfma_f32_16x16x32_bf16(
      __builtin_bit_cast(bf16x8, a), __builtin_bit_cast(bf16x8, b), c, 0, 0, 0);
}
// async global->LDS, 16B per lane; lds ptr must be wave-uniform base (HW adds lane*16)
static __device__ __forceinline__ void gload_lds16(const u16* g, u16* l) {
  __builtin_amdgcn_global_load_lds(
      (const __attribute__((address_space(1))) unsigned int*)g,
      (__attribute__((address_space(3))) unsigned int*)l, 16, 0, 0);
}

// ---------- problem constants ----------
#define BB 2
#define TT 2048
#define DD 2048
#define NH 16
#define NKVH 4
#define HD 128
#define MM (BB * TT)          // 4096 rows
#define QSTR 3072             // fused QKV projection row: [Q(2048) | K(512) | V(512)]

// ---------- fp32 -> bf16 convert ----------
__global__ __launch_bounds__(256) void cvt_f32_bf16(const float* __restrict__ in,
                                                    u16* __restrict__ out, int n4) {
  int stride = gridDim.x * blockDim.x;
  for (int i = blockIdx.x * blockDim.x + threadIdx.x; i < n4; i += stride) {
    float4v v = ((const float4v*)in)[i];
    u16x4 o;
    o[0] = f2b(v[0]); o[1] = f2b(v[1]); o[2] = f2b(v[2]); o[3] = f2b(v[3]);
    ((u16x4*)out)[i] = o;
  }
}

// ---------- RoPE in-place on bf16 (softmax scale folded in for Q) ----------
__global__ __launch_bounds__(256) void rope_kernel(u16* __restrict__ X,
                                                   const float* __restrict__ rope,
                                                   int n_heads, int rowstr, float scale) {
  int idx = blockIdx.x * 256 + threadIdx.x;
  int i  = idx & 63;
  int h  = (idx >> 6) % n_heads;
  int bt = idx / (64 * n_heads);
  int t  = bt & (TT - 1);
  size_t base = (size_t)bt * rowstr + h * HD + i;
  float x1 = b2f(X[base]);
  float x2 = b2f(X[base + 64]);
  float c = rope[t * 128 + 2 * i];
  float s = rope[t * 128 + 2 * i + 1];
  X[base]      = f2b(scale * (x1 * c - x2 * s));
  X[base + 64] = f2b(scale * (x1 * s + x2 * c));
}

// ---------- GEMM (m97 structure): C[M,N] = A[M,K] * W[N,K]^T ----------
// 128x128 tile, 4 waves (2x2), 64x64/wave, BK=32, linear LDS [128][32],
// staged via global_load_lds width=16.
template <bool OUTBF>
__global__ __launch_bounds__(256) void gemm_bt(const u16* __restrict__ A,
                                               const u16* __restrict__ W,
                                               void* __restrict__ Cout,
                                               int M, int N, int K) {
  __shared__ __align__(16) u16 As[128 * 32];
  __shared__ __align__(16) u16 Ws[128 * 32];
  const int tid = threadIdx.x, lane = tid & 63, wid = tid >> 6;
  const int wr = wid >> 1, wc = wid & 1;
  const int brow = blockIdx.y * 128, bcol = blockIdx.x * 128;
  const int l15 = lane & 15, lh = lane >> 4;

  // chunk c (16B): row = c>>2, elem col = (c&3)*8 ; LDS elem off = c*8
  const int c0 = wid * 64 + lane;
  const int c1 = c0 + 256;
  const u16* Ag0 = A + (size_t)(brow + (c0 >> 2)) * K + ((c0 & 3) << 3);
  const u16* Ag1 = A + (size_t)(brow + (c1 >> 2)) * K + ((c1 & 3) << 3);
  const u16* Wg0 = W + (size_t)(bcol + (c0 >> 2)) * K + ((c0 & 3) << 3);
  const u16* Wg1 = W + (size_t)(bcol + (c1 >> 2)) * K + ((c1 & 3) << 3);
  u16* lA0 = &As[(wid * 64) * 8];
  u16* lA1 = &As[(wid * 64 + 256) * 8];
  u16* lW0 = &Ws[(wid * 64) * 8];
  u16* lW1 = &Ws[(wid * 64 + 256) * 8];

  f32x4 acc[4][4];
#pragma unroll
  for (int m = 0; m < 4; ++m)
#pragma unroll
    for (int n = 0; n < 4; ++n) acc[m][n] = (f32x4)0.0f;

  for (int k0 = 0; k0 < K; k0 += 32) {
    __syncthreads();
    gload_lds16(Ag0 + k0, lA0);
    gload_lds16(Ag1 + k0, lA1);
    gload_lds16(Wg0 + k0, lW0);
    gload_lds16(Wg1 + k0, lW1);
    __syncthreads();
    short8 af[4], bfr[4];
#pragma unroll
    for (int m = 0; m < 4; ++m)
      af[m] = *(const short8*)&As[(wr * 64 + m * 16 + l15) * 32 + (lh << 3)];
#pragma unroll
    for (int n = 0; n < 4; ++n)
      bfr[n] = *(const short8*)&Ws[(wc * 64 + n * 16 + l15) * 32 + (lh << 3)];
#pragma unroll
    for (int m = 0; m < 4; ++m)
#pragma unroll
      for (int n = 0; n < 4; ++n)
        acc[m][n] = mfma_bf16(af[m], bfr[n], acc[m][n]);
  }

#pragma unroll
  for (int m = 0; m < 4; ++m)
#pragma unroll
    for (int n = 0; n < 4; ++n)
#pragma unroll
      for (int j = 0; j < 4; ++j) {
        int row = brow + wr * 64 + m * 16 + lh * 4 + j;
        int col = bcol + wc * 64 + n * 16 + l15;
        if (OUTBF)
          ((u16*)Cout)[(size_t)row * N + col] = f2b(acc[m][n][j]);
        else
          ((float*)Cout)[(size_t)row * N + col] = acc[m][n][j];
      }
}

// ---------- fused causal GQA flash attention ----------
// Round-0 data path (staged LDS K/V, T14 issue-early/write-late) restored.
// Change vs round-0: UNPAIRED q-tiles -> 512 blocks (2 blocks/CU so one
// block computes while the other sits at its staging barrier), qt-descending
// launch order (heavy blocks first), T5 setprio around MFMA clusters.
#define QBLK 128
#define KVBLK 64

static __device__ __forceinline__ void attn_tile(
    const short8* qa, f32x4* o, f32x4& ol, float* mrow,
    int qrow0, int kv0,
    const u16* Ks, const unsigned* Vt32, u16* myP,
    int l15, int lh, short8 ones8) {
  if (kv0 > qrow0 + 15) return;   // fully masked for this wave

  f32x4 s[4];
#pragma unroll
  for (int nt = 0; nt < 4; ++nt) s[nt] = (f32x4)0.0f;
  __builtin_amdgcn_s_setprio(1);
#pragma unroll
  for (int nt = 0; nt < 4; ++nt)
#pragma unroll
    for (int kk = 0; kk < 4; ++kk) {
      short8 kb = *(const short8*)&Ks[(nt * 16 + l15) * 136 + kk * 32 + (lh << 3)];
      s[nt] = mfma_bf16(qa[kk], kb, s[nt]);
    }
  __builtin_amdgcn_s_setprio(0);

  const int qg = qrow0 + lh * 4;
#pragma unroll
  for (int j = 0; j < 4; ++j)
#pragma unroll
    for (int nt = 0; nt < 4; ++nt)
      if (kv0 + nt * 16 + l15 > qg + j) s[nt][j] = -1e30f;

  float mt[4];
#pragma unroll
  for (int j = 0; j < 4; ++j)
    mt[j] = fmaxf(fmaxf(s[0][j], s[1][j]), fmaxf(s[2][j], s[3][j]));
#pragma unroll
  for (int d = 1; d <= 8; d <<= 1)
#pragma unroll
    for (int j = 0; j < 4; ++j) mt[j] = fmaxf(mt[j], __shfl_xor(mt[j], d));

  // defer-max (T13): rescale only when max grew by > 8
  float gmax = mt[0] - mrow[0];
#pragma unroll
  for (int j = 1; j < 4; ++j) gmax = fmaxf(gmax, mt[j] - mrow[j]);
  if (!__all(gmax <= 8.0f)) {
#pragma unroll
    for (int j = 0; j < 4; ++j) {
      float mn = fmaxf(mrow[j], mt[j]);
      float a = __expf(mrow[j] - mn);
      mrow[j] = mn;
      ol[j] *= a;
#pragma unroll
      for (int n = 0; n < 8; ++n) o[n][j] *= a;
    }
  }

  f32x4 p[4];
#pragma unroll
  for (int nt = 0; nt < 4; ++nt)
#pragma unroll
    for (int j = 0; j < 4; ++j) p[nt][j] = __expf(s[nt][j] - mrow[j]);

  // P -> per-wave LDS (transpose to A-frag layout)
#pragma unroll
  for (int nt = 0; nt < 4; ++nt)
#pragma unroll
    for (int j = 0; j < 4; ++j)
      myP[(lh * 4 + j) * 72 + nt * 16 + l15] = f2b(p[nt][j]);

  // PV (+ row-sum via ones-MFMA instead of shuffles)
  __builtin_amdgcn_s_setprio(1);
#pragma unroll
  for (int c = 0; c < 2; ++c) {
    short8 pa = *(const short8*)&myP[l15 * 72 + c * 32 + (lh << 3)];
    ol = mfma_bf16(pa, ones8, ol);
#pragma unroll
    for (int nt2 = 0; nt2 < 8; ++nt2) {
      int d = nt2 * 16 + l15;
      int byteoff = (d * 144 + (c * 32 + lh * 8) * 2) ^ (((d >> 3) & 7) << 4);
      short8 vb = *(const short8*)((const char*)Vt32 + byteoff);
      o[nt2] = mfma_bf16(pa, vb, o[nt2]);
    }
  }
  __builtin_amdgcn_s_setprio(0);
}

__global__ __launch_bounds__(512, 4) void attn_kernel(const u16* __restrict__ QKV,
                                                      u16* __restrict__ Y) {
  __shared__ __align__(16) u16 Ks[KVBLK * 136];      // 17408 B
  __shared__ __align__(16) unsigned Vt32[128 * 36];  // 18432 B
  __shared__ __align__(16) u16 Ps[8][16 * 72];       // 18432 B

  const int tid = threadIdx.x, lane = tid & 63, wid = tid >> 6;
  const int l15 = lane & 15, lh = lane >> 4;
  const int bid = blockIdx.x;
  const int qt = 15 - (bid >> 5);   // qt descending: heavy blocks first
  const int bh = bid & 31;
  const int h = bh & 15;
  const int b = bh >> 4;
  const int kvh = h >> 2;
  const int row0 = qt * QBLK + wid * 16;   // wave's 16 q rows

  const u16* Kb_ = QKV + (size_t)b * TT * QSTR + DD + kvh * HD;  // K cols
  const u16* Vb_ = Kb_ + NKVH * HD;                              // V cols

  short8 ones8;
#pragma unroll
  for (int e = 0; e < 8; ++e) ones8[e] = (short)0x3F80;  // bf16 1.0

  short8 qa[4];
  {
    const u16* qp = QKV + (size_t)(b * TT + row0 + l15) * QSTR + h * HD + (lh << 3);
#pragma unroll
    for (int kk = 0; kk < 4; ++kk) qa[kk] = *(const short8*)(qp + kk * 32);
  }

  f32x4 o[8];
  f32x4 ol = (f32x4)0.0f;
  float m[4];
#pragma unroll
  for (int n = 0; n < 8; ++n) o[n] = (f32x4)0.0f;
#pragma unroll
  for (int j = 0; j < 4; ++j) m[j] = -1e30f;

  const int ntile = (qt + 1) * (QBLK / KVBLK);

  // staging registers (T14: issue early, write late)
  short8 kreg0, kreg1, vreg0, vreg1;
  const int srow = tid >> 4;           // 0..31
  const int sc8 = (tid & 15) << 3;

  auto issue = [&](int kv0) {
    kreg0 = *(const short8*)&Kb_[(size_t)(kv0 + srow) * QSTR + sc8];
    kreg1 = *(const short8*)&Kb_[(size_t)(kv0 + 32 + srow) * QSTR + sc8];
    vreg0 = *(const short8*)&Vb_[(size_t)(kv0 + 2 * srow) * QSTR + sc8];
    vreg1 = *(const short8*)&Vb_[(size_t)(kv0 + 2 * srow + 1) * QSTR + sc8];
  };

  issue(0);
  for (int it = 0; it < ntile; ++it) {
    const int kv0 = it * KVBLK;
    __syncthreads();   // previous tile's LDS reads done
    // K rows srow, srow+32 (row-major, pad 136)
    *(short8*)&Ks[srow * 136 + sc8] = kreg0;
    *(short8*)&Ks[(srow + 32) * 136 + sc8] = kreg1;
    // V transposed as u32 kv-pairs, XOR-swizzled
#pragma unroll
    for (int e = 0; e < 8; ++e) {
      int d = sc8 + e;
      unsigned pack = (unsigned)(u16)vreg0[e] | ((unsigned)(u16)vreg1[e] << 16);
      int byteoff = (d * 144 + 4 * srow) ^ (((d >> 3) & 7) << 4);
      *(unsigned*)((char*)Vt32 + byteoff) = pack;
    }
    __syncthreads();   // staged tile visible
    if (it + 1 < ntile) issue(kv0 + KVBLK);  // overlap next loads with compute

    attn_tile(qa, o, ol, m, row0, kv0, Ks, Vt32, &Ps[wid][0], l15, lh, ones8);
  }

  f32x4 inv;
#pragma unroll
  for (int j = 0; j < 4; ++j) inv[j] = __builtin_amdgcn_rcpf(ol[j]);
#pragma unroll
  for (int nt = 0; nt < 8; ++nt)
#pragma unroll
    for (int j = 0; j < 4; ++j)
      Y[(size_t)(b * TT + row0 + lh * 4 + j) * DD + h * HD + nt * 16 + l15] =
          f2b(o[nt][j] * inv[j]);
}

// ---------- launcher ----------
extern "C" void kernel_launch(void* const* d_in, const int* in_sizes, int n_in,
                              void* d_out, int out_size, void* d_ws, size_t ws_size,
                              hipStream_t stream) {
  const float* x    = (const float*)d_in[0];
  const float* rope = (const float*)d_in[1];
  const float* wq   = (const float*)d_in[2];
  const float* wk   = (const float*)d_in[3];
  const float* wv   = (const float*)d_in[4];
  const float* wo   = (const float*)d_in[5];
  float* out = (float*)d_out;

  char* ws = (char*)d_ws;
  u16* xb    = (u16*)ws; ws += (size_t)MM * DD * 2;        // 16.8 MB
  u16* wqkvb = (u16*)ws; ws += (size_t)QSTR * DD * 2;      // 12.6 MB (wq|wk|wv rows)
  u16* wob   = (u16*)ws; ws += (size_t)DD * DD * 2;        //  8.4 MB
  u16* QKVb  = (u16*)ws; ws += (size_t)MM * QSTR * 2;      // 25.2 MB
  u16* Yb    = (u16*)ws;                                   // 16.8 MB

  // 1) converts (wq, wk, wv concatenated into one [3072][2048] weight)
  cvt_f32_bf16<<<2048, 256, 0, stream>>>(x,  xb,  (MM * DD) / 4);
  cvt_f32_bf16<<<2048, 256, 0, stream>>>(wq, wqkvb, (DD * DD) / 4);
  cvt_f32_bf16<<<1024, 256, 0, stream>>>(wk, wqkvb + (size_t)DD * DD, (NKVH * HD * DD) / 4);
  cvt_f32_bf16<<<1024, 256, 0, stream>>>(wv, wqkvb + (size_t)(DD + NKVH * HD) * DD, (NKVH * HD * DD) / 4);
  cvt_f32_bf16<<<2048, 256, 0, stream>>>(wo, wob, (DD * DD) / 4);

  // 2) fused QKV projection: one M=4096, N=3072, K=2048 GEMM
  gemm_bt<true><<<dim3(QSTR / 128, MM / 128), 256, 0, stream>>>(xb, wqkvb, QKVb, MM, QSTR, DD);

  // 3) RoPE (softmax scale folded into Q; V cols untouched)
  rope_kernel<<<(MM * NH * 64) / 256, 256, 0, stream>>>(QKVb, rope, NH, QSTR, 0.08838834764831845f);
  rope_kernel<<<(MM * NKVH * 64) / 256, 256, 0, stream>>>(QKVb + DD, rope, NKVH, QSTR, 1.0f);

  // 4) attention (unpaired q-tiles, 512 blocks, heavy first)
  attn_kernel<<<BB * NH * (TT / QBLK), 512, 0, stream>>>(QKVb, Yb);

  // 5) output projection (fp32 out)
  gemm_bt<false><<<dim3(DD / 128, MM / 128), 256, 0, stream>>>(Yb, wob, out, MM, DD, DD);
}

// Round 3
// 249.107 us; speedup vs baseline: 1.6196x; 1.1234x over previous
//
#include <hip/hip_runtime.h>

// ---------- types & helpers ----------
typedef unsigned short u16;
typedef float   f32x4  __attribute__((ext_vector_type(4)));
typedef short   short8 __attribute__((ext_vector_type(8)));
typedef __bf16  bf16x8 __attribute__((ext_vector_type(8)));
typedef float   float4v __attribute__((ext_vector_type(4)));
typedef unsigned short u16x4 __attribute__((ext_vector_type(4)));

static __device__ __forceinline__ u16 f2b(float f) {
  union { float f; unsigned u; } v; v.f = f;
  unsigned r = (v.u + 0x7fffu + ((v.u >> 16) & 1u)) >> 16;  // RNE
  return (u16)r;
}
static __device__ __forceinline__ float b2f(u16 h) {
  union { unsigned u; float f; } v; v.u = ((unsigned)h) << 16;
  return v.f;
}
static __device__ __forceinline__ f32x4 mfma_bf16(short8 a, short8 b, f32x4 c) {
  return __builtin_amdgcn_mfma_f32_16x16x32_bf16(
      __builtin_bit_cast(bf16x8, a), __builtin_bit_cast(bf16x8, b), c, 0, 0, 0);
}
// async global->LDS, 16B per lane; lds ptr must be wave-uniform base (HW adds lane*16)
static __device__ __forceinline__ void gload_lds16(const u16* g, u16* l) {
  __builtin_amdgcn_global_load_lds(
      (const __attribute__((address_space(1))) unsigned int*)g,
      (__attribute__((address_space(3))) unsigned int*)l, 16, 0, 0);
}

// ---------- problem constants ----------
#define BB 2
#define TT 2048
#define DD 2048
#define NH 16
#define NKVH 4
#define HD 128
#define MM (BB * TT)          // 4096 rows
#define QSTR 3072             // fused QKV projection row: [Q(2048) | K(512) | V(512)]

// ---------- fp32 -> bf16 convert ----------
__global__ __launch_bounds__(256) void cvt_f32_bf16(const float* __restrict__ in,
                                                    u16* __restrict__ out, int n4) {
  int stride = gridDim.x * blockDim.x;
  for (int i = blockIdx.x * blockDim.x + threadIdx.x; i < n4; i += stride) {
    float4v v = ((const float4v*)in)[i];
    u16x4 o;
    o[0] = f2b(v[0]); o[1] = f2b(v[1]); o[2] = f2b(v[2]); o[3] = f2b(v[3]);
    ((u16x4*)out)[i] = o;
  }
}

// ---------- RoPE in-place on bf16 (softmax scale folded in for Q) ----------
__global__ __launch_bounds__(256) void rope_kernel(u16* __restrict__ X,
                                                   const float* __restrict__ rope,
                                                   int n_heads, int rowstr, float scale) {
  int idx = blockIdx.x * 256 + threadIdx.x;
  int i  = idx & 63;
  int h  = (idx >> 6) % n_heads;
  int bt = idx / (64 * n_heads);
  int t  = bt & (TT - 1);
  size_t base = (size_t)bt * rowstr + h * HD + i;
  float x1 = b2f(X[base]);
  float x2 = b2f(X[base + 64]);
  float c = rope[t * 128 + 2 * i];
  float s = rope[t * 128 + 2 * i + 1];
  X[base]      = f2b(scale * (x1 * c - x2 * s));
  X[base + 64] = f2b(scale * (x1 * s + x2 * c));
}

// ---------- GEMM (m97 structure): C[M,N] = A[M,K] * W[N,K]^T ----------
template <bool OUTBF>
__global__ __launch_bounds__(256) void gemm_bt(const u16* __restrict__ A,
                                               const u16* __restrict__ W,
                                               void* __restrict__ Cout,
                                               int M, int N, int K) {
  __shared__ __align__(16) u16 As[128 * 32];
  __shared__ __align__(16) u16 Ws[128 * 32];
  const int tid = threadIdx.x, lane = tid & 63, wid = tid >> 6;
  const int wr = wid >> 1, wc = wid & 1;
  const int brow = blockIdx.y * 128, bcol = blockIdx.x * 128;
  const int l15 = lane & 15, lh = lane >> 4;

  const int c0 = wid * 64 + lane;
  const int c1 = c0 + 256;
  const u16* Ag0 = A + (size_t)(brow + (c0 >> 2)) * K + ((c0 & 3) << 3);
  const u16* Ag1 = A + (size_t)(brow + (c1 >> 2)) * K + ((c1 & 3) << 3);
  const u16* Wg0 = W + (size_t)(bcol + (c0 >> 2)) * K + ((c0 & 3) << 3);
  const u16* Wg1 = W + (size_t)(bcol + (c1 >> 2)) * K + ((c1 & 3) << 3);
  u16* lA0 = &As[(wid * 64) * 8];
  u16* lA1 = &As[(wid * 64 + 256) * 8];
  u16* lW0 = &Ws[(wid * 64) * 8];
  u16* lW1 = &Ws[(wid * 64 + 256) * 8];

  f32x4 acc[4][4];
#pragma unroll
  for (int m = 0; m < 4; ++m)
#pragma unroll
    for (int n = 0; n < 4; ++n) acc[m][n] = (f32x4)0.0f;

  for (int k0 = 0; k0 < K; k0 += 32) {
    __syncthreads();
    gload_lds16(Ag0 + k0, lA0);
    gload_lds16(Ag1 + k0, lA1);
    gload_lds16(Wg0 + k0, lW0);
    gload_lds16(Wg1 + k0, lW1);
    __syncthreads();
    short8 af[4], bfr[4];
#pragma unroll
    for (int m = 0; m < 4; ++m)
      af[m] = *(const short8*)&As[(wr * 64 + m * 16 + l15) * 32 + (lh << 3)];
#pragma unroll
    for (int n = 0; n < 4; ++n)
      bfr[n] = *(const short8*)&Ws[(wc * 64 + n * 16 + l15) * 32 + (lh << 3)];
#pragma unroll
    for (int m = 0; m < 4; ++m)
#pragma unroll
      for (int n = 0; n < 4; ++n)
        acc[m][n] = mfma_bf16(af[m], bfr[n], acc[m][n]);
  }

#pragma unroll
  for (int m = 0; m < 4; ++m)
#pragma unroll
    for (int n = 0; n < 4; ++n)
#pragma unroll
      for (int j = 0; j < 4; ++j) {
        int row = brow + wr * 64 + m * 16 + lh * 4 + j;
        int col = bcol + wc * 64 + n * 16 + l15;
        if (OUTBF)
          ((u16*)Cout)[(size_t)row * N + col] = f2b(acc[m][n][j]);
        else
          ((float*)Cout)[(size_t)row * N + col] = acc[m][n][j];
      }
}

// ---------- fused causal GQA flash attention ----------
// LDS-read-BW attack: each wave owns 32 q-rows (2 fragment-groups) and loads
// every K/V fragment ONCE for both groups (halves frag reads vs round-0).
// 4 waves / 256 threads per block (128 q-rows = one qt), grid 512, 2 blocks/CU.
// qt mapping pairs (15-i, i) so each CU's two blocks sum to a uniform 34 tiles.
// Staging identical to round-0: T14 reg round-trip, V u32-pack + XOR swizzle.
#define KVBLK 64

__global__ __launch_bounds__(256, 2) void attn_kernel(const u16* __restrict__ QKV,
                                                      u16* __restrict__ Y) {
  __shared__ __align__(16) u16 Ks[KVBLK * 136];      // 17408 B
  __shared__ __align__(16) unsigned Vt32[128 * 36];  // 18432 B
  __shared__ __align__(16) u16 Ps[4][2][16 * 72];    // 18432 B

  const int tid = threadIdx.x, lane = tid & 63, wid = tid >> 6;  // wid 0..3
  const int l15 = lane & 15, lh = lane >> 4;
  const int bid = blockIdx.x;
  const int g5 = bid >> 5;                       // 0..15
  const int qt = (g5 < 8) ? 15 - g5 : g5 - 8;    // halves pair to uniform load
  const int bh = bid & 31;
  const int h = bh & 15;
  const int b = bh >> 4;
  const int kvh = h >> 2;
  const int row0 = qt * 128 + wid * 32;          // wave's 32 q rows

  const u16* Kb_ = QKV + (size_t)b * TT * QSTR + DD + kvh * HD;  // K cols
  const u16* Vb_ = Kb_ + NKVH * HD;                              // V cols

  short8 ones8;
#pragma unroll
  for (int e = 0; e < 8; ++e) ones8[e] = (short)0x3F80;  // bf16 1.0

  short8 qa[2][4];
#pragma unroll
  for (int g = 0; g < 2; ++g) {
    const u16* qp = QKV + (size_t)(b * TT + row0 + g * 16 + l15) * QSTR + h * HD + (lh << 3);
#pragma unroll
    for (int kk = 0; kk < 4; ++kk) qa[g][kk] = *(const short8*)(qp + kk * 32);
  }

  f32x4 o[2][8];
  f32x4 ol[2];
  float m[2][4];
#pragma unroll
  for (int g = 0; g < 2; ++g) {
    ol[g] = (f32x4)0.0f;
#pragma unroll
    for (int n = 0; n < 8; ++n) o[g][n] = (f32x4)0.0f;
#pragma unroll
    for (int j = 0; j < 4; ++j) m[g][j] = -1e30f;
  }

  u16* myP0 = &Ps[wid][0][0];
  u16* myP1 = &Ps[wid][1][0];

  const int ntile = (qt + 1) * 2;

  // staging registers (T14: issue early, write late); 256 threads cover the tile
  short8 kreg[4], vreg[4];
  const int srow = tid >> 4;           // 0..15
  const int sc8 = (tid & 15) << 3;

  auto issue = [&](int kv0) {
#pragma unroll
    for (int i = 0; i < 4; ++i)
      kreg[i] = *(const short8*)&Kb_[(size_t)(kv0 + srow + 16 * i) * QSTR + sc8];
    vreg[0] = *(const short8*)&Vb_[(size_t)(kv0 + 2 * srow) * QSTR + sc8];
    vreg[1] = *(const short8*)&Vb_[(size_t)(kv0 + 2 * srow + 1) * QSTR + sc8];
    vreg[2] = *(const short8*)&Vb_[(size_t)(kv0 + 2 * srow + 32) * QSTR + sc8];
    vreg[3] = *(const short8*)&Vb_[(size_t)(kv0 + 2 * srow + 33) * QSTR + sc8];
  };

  issue(0);
  for (int it = 0; it < ntile; ++it) {
    const int kv0 = it * KVBLK;
    __syncthreads();   // previous tile's LDS reads done
    // K rows srow+16i (row-major, pad 136)
#pragma unroll
    for (int i = 0; i < 4; ++i)
      *(short8*)&Ks[(srow + 16 * i) * 136 + sc8] = kreg[i];
    // V transposed as u32 kv-pairs, XOR-swizzled
#pragma unroll
    for (int e = 0; e < 8; ++e) {
      int d = sc8 + e;
      unsigned pk0 = (unsigned)(u16)vreg[0][e] | ((unsigned)(u16)vreg[1][e] << 16);
      unsigned pk1 = (unsigned)(u16)vreg[2][e] | ((unsigned)(u16)vreg[3][e] << 16);
      int swz = ((d >> 3) & 7) << 4;
      *(unsigned*)((char*)Vt32 + ((d * 144 + 4 * srow) ^ swz)) = pk0;
      *(unsigned*)((char*)Vt32 + ((d * 144 + 4 * (srow + 16)) ^ swz)) = pk1;
    }
    __syncthreads();   // staged tile visible
    if (it + 1 < ntile) issue(kv0 + KVBLK);  // overlap next loads with compute

    if (kv0 > row0 + 31) continue;  // wave fully masked (keeps barriers above)

    // ---- QK^T: each K fragment read once, applied to both groups
    f32x4 s[2][4];
#pragma unroll
    for (int g = 0; g < 2; ++g)
#pragma unroll
      for (int nt = 0; nt < 4; ++nt) s[g][nt] = (f32x4)0.0f;

    __builtin_amdgcn_s_setprio(1);
#pragma unroll
    for (int nt = 0; nt < 4; ++nt) {
      const u16* krow = &Ks[(nt * 16 + l15) * 136 + (lh << 3)];
#pragma unroll
      for (int kk = 0; kk < 4; ++kk) {
        short8 kb = *(const short8*)(krow + kk * 32);
        s[0][nt] = mfma_bf16(qa[0][kk], kb, s[0][nt]);
        s[1][nt] = mfma_bf16(qa[1][kk], kb, s[1][nt]);
      }
    }
    __builtin_amdgcn_s_setprio(0);

    // ---- causal mask (diagonal tiles only; wave-uniform test)
    if (kv0 + 63 > row0) {
#pragma unroll
      for (int g = 0; g < 2; ++g) {
        const int qg = row0 + g * 16 + lh * 4;
#pragma unroll
        for (int j = 0; j < 4; ++j)
#pragma unroll
          for (int nt = 0; nt < 4; ++nt)
            if (kv0 + nt * 16 + l15 > qg + j) s[g][nt][j] = -1e30f;
      }
    }

    // ---- row max (16-lane groups via shfl_xor)
    float mt[2][4];
#pragma unroll
    for (int g = 0; g < 2; ++g)
#pragma unroll
      for (int j = 0; j < 4; ++j)
        mt[g][j] = fmaxf(fmaxf(s[g][0][j], s[g][1][j]), fmaxf(s[g][2][j], s[g][3][j]));
#pragma unroll
    for (int d = 1; d <= 8; d <<= 1)
#pragma unroll
      for (int g = 0; g < 2; ++g)
#pragma unroll
        for (int j = 0; j < 4; ++j) mt[g][j] = fmaxf(mt[g][j], __shfl_xor(mt[g][j], d));

    // ---- defer-max (T13): rescale only when max grew by > 8
    float gmax = mt[0][0] - m[0][0];
#pragma unroll
    for (int g = 0; g < 2; ++g)
#pragma unroll
      for (int j = 0; j < 4; ++j) gmax = fmaxf(gmax, mt[g][j] - m[g][j]);
    if (!__all(gmax <= 8.0f)) {
#pragma unroll
      for (int g = 0; g < 2; ++g)
#pragma unroll
        for (int j = 0; j < 4; ++j) {
          float mn = fmaxf(m[g][j], mt[g][j]);
          float a = __expf(m[g][j] - mn);
          m[g][j] = mn;
          ol[g][j] *= a;
#pragma unroll
          for (int n = 0; n < 8; ++n) o[g][n][j] *= a;
        }
    }

    // ---- P -> per-wave LDS (transpose to A-frag layout)
#pragma unroll
    for (int nt = 0; nt < 4; ++nt)
#pragma unroll
      for (int j = 0; j < 4; ++j) {
        myP0[(lh * 4 + j) * 72 + nt * 16 + l15] = f2b(__expf(s[0][nt][j] - m[0][j]));
        myP1[(lh * 4 + j) * 72 + nt * 16 + l15] = f2b(__expf(s[1][nt][j] - m[1][j]));
      }

    // ---- PV: each V fragment read once, applied to both groups
    __builtin_amdgcn_s_setprio(1);
#pragma unroll
    for (int c = 0; c < 2; ++c) {
      short8 pa0 = *(const short8*)&myP0[l15 * 72 + c * 32 + (lh << 3)];
      short8 pa1 = *(const short8*)&myP1[l15 * 72 + c * 32 + (lh << 3)];
      ol[0] = mfma_bf16(pa0, ones8, ol[0]);
      ol[1] = mfma_bf16(pa1, ones8, ol[1]);
#pragma unroll
      for (int nt2 = 0; nt2 < 8; ++nt2) {
        int d = nt2 * 16 + l15;
        int byteoff = (d * 144 + (c * 32 + lh * 8) * 2) ^ (((d >> 3) & 7) << 4);
        short8 vb = *(const short8*)((const char*)Vt32 + byteoff);
        o[0][nt2] = mfma_bf16(pa0, vb, o[0][nt2]);
        o[1][nt2] = mfma_bf16(pa1, vb, o[1][nt2]);
      }
    }
    __builtin_amdgcn_s_setprio(0);
  }

  // ---- epilogue
#pragma unroll
  for (int g = 0; g < 2; ++g) {
    f32x4 inv;
#pragma unroll
    for (int j = 0; j < 4; ++j) inv[j] = __builtin_amdgcn_rcpf(ol[g][j]);
#pragma unroll
    for (int nt2 = 0; nt2 < 8; ++nt2)
#pragma unroll
      for (int j = 0; j < 4; ++j)
        Y[(size_t)(b * TT + row0 + g * 16 + lh * 4 + j) * DD + h * HD + nt2 * 16 + l15] =
            f2b(o[g][nt2][j] * inv[j]);
  }
}

// ---------- launcher ----------
extern "C" void kernel_launch(void* const* d_in, const int* in_sizes, int n_in,
                              void* d_out, int out_size, void* d_ws, size_t ws_size,
                              hipStream_t stream) {
  const float* x    = (const float*)d_in[0];
  const float* rope = (const float*)d_in[1];
  const float* wq   = (const float*)d_in[2];
  const float* wk   = (const float*)d_in[3];
  const float* wv   = (const float*)d_in[4];
  const float* wo   = (const float*)d_in[5];
  float* out = (float*)d_out;

  char* ws = (char*)d_ws;
  u16* xb    = (u16*)ws; ws += (size_t)MM * DD * 2;        // 16.8 MB
  u16* wqkvb = (u16*)ws; ws += (size_t)QSTR * DD * 2;      // 12.6 MB (wq|wk|wv rows)
  u16* wob   = (u16*)ws; ws += (size_t)DD * DD * 2;        //  8.4 MB
  u16* QKVb  = (u16*)ws; ws += (size_t)MM * QSTR * 2;      // 25.2 MB
  u16* Yb    = (u16*)ws;                                   // 16.8 MB

  // 1) converts (wq, wk, wv concatenated into one [3072][2048] weight)
  cvt_f32_bf16<<<2048, 256, 0, stream>>>(x,  xb,  (MM * DD) / 4);
  cvt_f32_bf16<<<2048, 256, 0, stream>>>(wq, wqkvb, (DD * DD) / 4);
  cvt_f32_bf16<<<1024, 256, 0, stream>>>(wk, wqkvb + (size_t)DD * DD, (NKVH * HD * DD) / 4);
  cvt_f32_bf16<<<1024, 256, 0, stream>>>(wv, wqkvb + (size_t)(DD + NKVH * HD) * DD, (NKVH * HD * DD) / 4);
  cvt_f32_bf16<<<2048, 256, 0, stream>>>(wo, wob, (DD * DD) / 4);

  // 2) fused QKV projection: one M=4096, N=3072, K=2048 GEMM
  gemm_bt<true><<<dim3(QSTR / 128, MM / 128), 256, 0, stream>>>(xb, wqkvb, QKVb, MM, QSTR, DD);

  // 3) RoPE (softmax scale folded into Q; V cols untouched)
  rope_kernel<<<(MM * NH * 64) / 256, 256, 0, stream>>>(QKVb, rope, NH, QSTR, 0.08838834764831845f);
  rope_kernel<<<(MM * NKVH * 64) / 256, 256, 0, stream>>>(QKVb + DD, rope, NKVH, QSTR, 1.0f);

  // 4) attention (32-row waves, shared frag loads, 512 blocks, 2/CU)
  attn_kernel<<<512, 256, 0, stream>>>(QKVb, Yb);

  // 5) output projection (fp32 out)
  gemm_bt<false><<<dim3(DD / 128, MM / 128), 256, 0, stream>>>(Yb, wob, out, MM, DD, DD);
}